// Round 6
// baseline (172.808 us; speedup 1.0000x reference)
//
#include <hip/hip_runtime.h>
#include <stdint.h>

// ---------------- constants ----------------
constexpr int IMG     = 3072;
constexpr int NPIX    = IMG * IMG;        // 9437184
constexpr int PH      = 384;              // patch height/width
constexpr int NPATCH  = 64;
constexpr int NSLICE  = 8;                // slices per patch (48 rows each)
constexpr int SROWS   = PH / NSLICE;      // 48
constexpr int SEGCAP  = 6144;             // per-slice candidate capacity (exp 4608, +26 sigma)
constexpr int WPR     = IMG / 32;         // 96 words per row
constexpr int NWORDS  = NPIX / 32;        // 294912 = 1152*256 exactly
constexpr uint32_t KEY_LO = 0x3F000000u;  // bits(0.5f)
constexpr uint32_t KEY_HI = 0x3F800000u;  // bits(1.0f)
constexpr uint32_t WLO    = 0x3F400000u;  // bits(0.75f) — candidate window lower bound
constexpr int NBW     = 4096;             // window bins of 1024 ulps: (key-WLO)>>10
// Exact fp32 bit-step of +-5e-5f for th in [0.5,1): +-839 ulps per step (no RNE ties)
constexpr int STEP_ULPS = 839;
constexpr int TR = 12;                    // close_store rows/block; 3072/12 = 256 blocks

// ---------------- workspace layout (bytes) ----------------
constexpr size_t OFF_VB   = 0;                                    // 128 u32
constexpr size_t OFF_CNTS = 512;                                  // 512 u32
constexpr size_t OFF_SEG  = 4096;                                 // 512*SEGCAP u32
constexpr size_t OFF_B    = OFF_SEG + (size_t)512 * SEGCAP * 4;   // packed binary

__device__ __forceinline__ bool is_frame(int p) {
    int pr = p >> 3, pc = p & 7;
    return pr == 0 || pr == 7 || pc == 0 || pc == 7;
}

// Integer count boundaries reproducing fp32 mean/compare semantics (verified R1-R5)
__device__ void compute_ranks(bool frame, int& R1, int& R2) {
    float fb = frame ? 0.05f : 0.0f;
    float lo = 0.12f - fb;
    float hi = 0.08f - fb;
    int c = (int)((double)lo * 147456.0);
    while (c > 0 && (float)(c - 1) / 147456.0f >= lo) --c;
    while ((float)c / 147456.0f < lo) ++c;
    int d = (int)((double)hi * 147456.0);
    while ((float)(d + 1) / 147456.0f <= hi) ++d;
    while (d > 0 && (float)d / 147456.0f > hi) --d;
    R1 = c - 1;   // 0-indexed descending rank of v1 (K_lo-th largest)
    R2 = d;       // 0-indexed descending rank of v2 ((C_hi+1)-th largest)
}

// ---------------- K1: candidate compaction (single x read, no global atomics) --
// 512 blocks = 64 patches x 8 slices of 48 rows. Window keys (>= 0.75) appended
// to a private per-slice segment. LDS counter is wave-aggregated by the compiler;
// consecutive lanes get consecutive slots -> coalesced stores.
__global__ __launch_bounds__(256) void k_seg(const float* __restrict__ x,
                                             uint32_t* __restrict__ seg,
                                             uint32_t* __restrict__ cnt_s) {
    __shared__ uint32_t lcnt;
    const int p = blockIdx.x >> 3, s = blockIdx.x & 7;
    const int t = threadIdx.x;
    const int pr = p >> 3, pc = p & 7;
    const float* base = x + (size_t)(pr * PH + s * SROWS) * IMG + pc * PH;
    uint32_t* myseg = seg + (size_t)blockIdx.x * SEGCAP;

    if (t == 0) lcnt = 0;
    __syncthreads();

    constexpr int NF4 = SROWS * (PH / 4);  // 4608
    for (int i = t; i < NF4; i += 256) {
        int r = i / 96, c = i - r * 96;
        float4 v = *reinterpret_cast<const float4*>(base + (size_t)r * IMG + c * 4);
        float vals[4] = {v.x, v.y, v.z, v.w};
#pragma unroll
        for (int k = 0; k < 4; ++k) {
            uint32_t key = __float_as_uint(vals[k]);
            if (key >= WLO) {   // uniform [0,1): keys < 0.5 have key < KEY_LO < WLO
                uint32_t idx = atomicAdd(&lcnt, 1u);
                if (idx < SEGCAP) myseg[idx] = key;
            }
        }
    }
    __syncthreads();
    if (t == 0) cnt_s[blockIdx.x] = (lcnt < SEGCAP) ? lcnt : SEGCAP;
}

// ---------------- K2: exact two-level radix select over segments --------------
// One block per patch, 512 threads. Level 1: 4096 bins of 1024 ulps over
// [0.75, 1.0). Level 2: 1-ulp sub-hist of the two rank-selected bins.
__global__ __launch_bounds__(512) void k_sel(const uint32_t* __restrict__ seg,
                                             const uint32_t* __restrict__ cnt_s,
                                             uint32_t* __restrict__ vbits) {
    __shared__ uint32_t hist[NBW];        // 16 KB
    __shared__ uint32_t part1[512];       // 8 desc bins each
    __shared__ uint32_t part2[32];        // 16 part1 each (128 desc bins)
    __shared__ uint32_t sub[2][1024];     // 8 KB
    __shared__ uint32_t spart[128];       // 16 desc sub-bins each
    __shared__ uint32_t above_s;
    __shared__ uint32_t selb[2], selr[2];
    __shared__ uint32_t ns[NSLICE];

    const int p = blockIdx.x;
    const int t = threadIdx.x;
    if (t < NSLICE) ns[t] = cnt_s[p * NSLICE + t];
    for (int i = t; i < NBW; i += 512) hist[i] = 0;
    if (t == 0) above_s = 0;
    __syncthreads();

    // level-1 histogram over the 8 segments
    for (int s = 0; s < NSLICE; ++s) {
        const uint32_t* sg = seg + (size_t)(p * NSLICE + s) * SEGCAP;
        uint32_t n = ns[s];
        for (uint32_t i = t; i < n; i += 512) {
            uint32_t key = sg[i];
            if (key >= KEY_HI) atomicAdd(&above_s, 1u);
            else               atomicAdd(&hist[(key - WLO) >> 10], 1u);
        }
    }
    __syncthreads();
    {
        uint32_t sum = 0;
#pragma unroll
        for (int b = 0; b < 8; ++b) sum += hist[NBW - 1 - (8 * t + b)];
        part1[t] = sum;
    }
    __syncthreads();
    if (t < 32) {
        uint32_t sum = 0;
#pragma unroll
        for (int k = 0; k < 16; ++k) sum += part1[16 * t + k];
        part2[t] = sum;
    }
    __syncthreads();
    if (t == 0) {
        uint32_t above = above_s;
        uint32_t total = above;
        for (int u = 0; u < 32; ++u) total += part2[u];
        int R[2];
        compute_ranks(is_frame(p), R[0], R[1]);
        for (int j = 0; j < 2; ++j) {
            int rank = R[j];
            if (rank < (int)above)  rank = (int)above;       // safety: v >= 1.0
            if (rank >= (int)total) rank = (int)total - 1;   // safety: window underflow
            uint32_t cum = above;
            int u = 31;
            for (int i = 0; i < 32; ++i) {
                if ((uint32_t)rank < cum + part2[i]) { u = i; break; }
                cum += part2[i];
            }
            int kk = 15;
            for (int i = 0; i < 16; ++i) {
                if ((uint32_t)rank < cum + part1[16 * u + i]) { kk = i; break; }
                cum += part1[16 * u + i];
            }
            int base_d = 8 * (16 * u + kk);
            uint32_t bin = NBW - 1 - base_d, r = 0;
            for (int b = 0; b < 8; ++b) {
                uint32_t h = hist[NBW - 1 - (base_d + b)];
                if ((uint32_t)rank < cum + h) { bin = NBW - 1 - (base_d + b); r = (uint32_t)rank - cum; break; }
                cum += h;
            }
            selb[j] = bin;
            selr[j] = r;
        }
    }
    for (int i = t; i < 1024; i += 512) { sub[0][i] = 0; sub[1][i] = 0; }
    __syncthreads();

    // level-2: 1-ulp sub-hist of the two selected bins
    {
        const uint32_t b0 = selb[0], b1 = selb[1];
        for (int s = 0; s < NSLICE; ++s) {
            const uint32_t* sg = seg + (size_t)(p * NSLICE + s) * SEGCAP;
            uint32_t n = ns[s];
            for (uint32_t i = t; i < n; i += 512) {
                uint32_t key = sg[i];
                if (key < KEY_HI) {
                    uint32_t bin = (key - WLO) >> 10;
                    uint32_t sb  = key & 1023u;
                    if (bin == b0) atomicAdd(&sub[0][sb], 1u);
                    if (bin == b1) atomicAdd(&sub[1][sb], 1u);
                }
            }
        }
    }
    __syncthreads();
    if (t < 128) {
        int j = t >> 6, u = t & 63;
        uint32_t sum = 0;
#pragma unroll
        for (int k = 0; k < 16; ++k) sum += sub[j][1023 - (16 * u + k)];
        spart[t] = sum;
    }
    __syncthreads();
    if (t == 0 || t == 64) {
        int j = t >> 6;
        uint32_t rank = selr[j];
        uint32_t cum = 0, subbin = 0;
        int u = 63;
        for (int i = 0; i < 64; ++i) {
            if (rank < cum + spart[j * 64 + i]) { u = i; break; }
            cum += spart[j * 64 + i];
        }
        for (int i = 0; i < 16; ++i) {
            int d = 16 * u + i;
            uint32_t h = sub[j][1023 - d];
            if (rank < cum + h) { subbin = (uint32_t)(1023 - d); break; }
            cum += h;
        }
        vbits[p * 2 + j] = WLO + (selb[j] << 10) + subbin;
    }
}

// ---------------- pack: th chain (in-block) + binarize + bit-pack (verified) ---
__global__ __launch_bounds__(256) void k_pack(const float* __restrict__ x,
                                              const uint32_t* __restrict__ vbits,
                                              uint32_t* __restrict__ B) {
    __shared__ uint32_t vb[128];
    __shared__ float ths_s[NPATCH];
    int t = threadIdx.x;
    if (t < 128) vb[t] = vbits[t];
    __syncthreads();
    if (t == 0) {
        uint32_t b = 0x3F59999Au;  // bits(0.85f)
        for (int p = 0; p < NPATCH; ++p) {
            uint32_t bv1 = vb[2 * p], bv2 = vb[2 * p + 1];
            int d1 = (int)b - (int)bv1;
            if (d1 >= 0) b -= (uint32_t)(STEP_ULPS * (d1 / STEP_ULPS + 1));
            int d2 = (int)bv2 - (int)b;
            if (d2 > 0) b += (uint32_t)(STEP_ULPS * ((d2 + STEP_ULPS - 1) / STEP_ULPS));
            ths_s[p] = __uint_as_float(b);
        }
    }
    __syncthreads();
    int wi = blockIdx.x * 256 + t;
    if (wi >= NWORDS) return;
    int y  = wi / WPR;
    int wx = wi - y * WPR;
    float th = ths_s[(y / PH) * 8 + (wx * 32) / PH];
    const float* row = x + (size_t)y * IMG + wx * 32;
    uint32_t m = 0;
#pragma unroll
    for (int k = 0; k < 8; ++k) {
        float4 v = *reinterpret_cast<const float4*>(row + 4 * k);
        m |= (uint32_t)(v.x > th) << (4 * k + 0);
        m |= (uint32_t)(v.y > th) << (4 * k + 1);
        m |= (uint32_t)(v.z > th) << (4 * k + 2);
        m |= (uint32_t)(v.w > th) << (4 * k + 3);
    }
    B[wi] = m;
}

// ---------------- fused 5x5 close + f32 store, row-tile + halo in LDS ----------
__device__ __forceinline__ uint32_t hshift5_or(uint32_t c, uint32_t l, uint32_t r) {
    uint64_t xr = ((uint64_t)r << 32) | c;
    uint64_t xl = ((uint64_t)c << 32) | l;
    return c | (uint32_t)(xr >> 1) | (uint32_t)(xr >> 2)
             | (uint32_t)(xl >> 31) | (uint32_t)(xl >> 30);
}
__device__ __forceinline__ uint32_t hshift5_and(uint32_t c, uint32_t l, uint32_t r) {
    uint64_t xr = ((uint64_t)r << 32) | c;
    uint64_t xl = ((uint64_t)c << 32) | l;
    return c & (uint32_t)(xr >> 1) & (uint32_t)(xr >> 2)
             & (uint32_t)(xl >> 31) & (uint32_t)(xl >> 30);
}

__global__ __launch_bounds__(256) void k_close_store(const uint32_t* __restrict__ B,
                                                     float* __restrict__ out) {
    __shared__ uint32_t Bs[TR + 8][WPR];   // binary rows [y0-4, y0+TR+4)
    __shared__ uint32_t Ds[TR + 4][WPR];   // dilated rows [y0-2, y0+TR+2)
    const int y0 = blockIdx.x * TR;
    const int t = threadIdx.x;

    for (int i = t; i < (TR + 8) * WPR; i += 256) {
        int r = i / WPR, c = i - r * WPR;
        int gy = y0 - 4 + r;
        Bs[r][c] = (gy >= 0 && gy < IMG) ? B[gy * WPR + c] : 0u;
    }
    __syncthreads();

    for (int i = t; i < (TR + 4) * WPR; i += 256) {
        int r = i / WPR, c = i - r * WPR;
        uint32_t acc = 0;
#pragma unroll
        for (int dy = -2; dy <= 2; ++dy) {
            int br = r + 2 + dy;
            uint32_t cc = Bs[br][c];
            uint32_t ll = (c > 0)       ? Bs[br][c - 1] : 0u;
            uint32_t rr = (c < WPR - 1) ? Bs[br][c + 1] : 0u;
            acc |= hshift5_or(cc, ll, rr);
        }
        Ds[r][c] = acc;
    }
    __syncthreads();

    for (int i = t; i < TR * WPR; i += 256) {
        int r = i / WPR, c = i - r * WPR;
        int gy = y0 + r;
        uint32_t acc = 0xFFFFFFFFu;
#pragma unroll
        for (int dy = -2; dy <= 2; ++dy) {
            int yy = gy + dy;
            if (yy < 0 || yy >= IMG) continue;
            int dr = r + 2 + dy;
            uint32_t cc = Ds[dr][c];
            uint32_t ll = (c > 0)       ? Ds[dr][c - 1] : 0xFFFFFFFFu;
            uint32_t rr = (c < WPR - 1) ? Ds[dr][c + 1] : 0xFFFFFFFFu;
            acc &= hshift5_and(cc, ll, rr);
        }
        float* o = out + (size_t)gy * IMG + c * 32;
#pragma unroll
        for (int k = 0; k < 8; ++k) {
            float4 v;
            v.x = (acc & (1u << (4 * k + 0))) ? 1.0f : 0.0f;
            v.y = (acc & (1u << (4 * k + 1))) ? 1.0f : 0.0f;
            v.z = (acc & (1u << (4 * k + 2))) ? 1.0f : 0.0f;
            v.w = (acc & (1u << (4 * k + 3))) ? 1.0f : 0.0f;
            *reinterpret_cast<float4*>(o + 4 * k) = v;
        }
    }
}

extern "C" void kernel_launch(void* const* d_in, const int* in_sizes, int n_in,
                              void* d_out, int out_size, void* d_ws, size_t ws_size,
                              hipStream_t stream) {
    const float* x = (const float*)d_in[0];
    float* out = (float*)d_out;
    uint8_t* ws = (uint8_t*)d_ws;

    uint32_t* vbits = (uint32_t*)(ws + OFF_VB);
    uint32_t* cnt_s = (uint32_t*)(ws + OFF_CNTS);
    uint32_t* seg   = (uint32_t*)(ws + OFF_SEG);
    uint32_t* Bb    = (uint32_t*)(ws + OFF_B);

    int gw = NWORDS / 256;  // 1152, exact

    k_seg<<<NPATCH * NSLICE, 256, 0, stream>>>(x, seg, cnt_s);
    k_sel<<<NPATCH, 512, 0, stream>>>(seg, cnt_s, vbits);
    k_pack<<<gw, 256, 0, stream>>>(x, vbits, Bb);
    k_close_store<<<IMG / TR, 256, 0, stream>>>(Bb, out);
}

// Round 7
// 167.303 us; speedup vs baseline: 1.0329x; 1.0329x over previous
//
#include <hip/hip_runtime.h>
#include <stdint.h>

// ---------------- constants ----------------
constexpr int IMG     = 3072;
constexpr int NPIX    = IMG * IMG;        // 9437184
constexpr int PH      = 384;              // patch height/width
constexpr int NPATCH  = 64;
constexpr int NSLICE  = 8;                // slices per patch (48 rows each)
constexpr int SROWS   = PH / NSLICE;      // 48
constexpr int NBC     = 1024;             // coarse bins over [0.5,1): (key-KEY_LO)>>13
constexpr int SEGCAP  = 6144;             // per-slice window-key capacity (exp 4608, +26 sigma)
constexpr int CAP     = 2048;             // per-(patch,j) candidate list capacity (exp ~144)
constexpr int WPR     = IMG / 32;         // 96 words per row
constexpr int NWORDS  = NPIX / 32;        // 294912 = 1152*256 exactly
constexpr uint32_t KEY_LO = 0x3F000000u;  // bits(0.5f)
constexpr uint32_t KEY_HI = 0x3F800000u;  // bits(1.0f)
constexpr uint32_t WLO    = 0x3F400000u;  // bits(0.75f) — candidate window lower bound
// Exact fp32 bit-step of +-5e-5f for th in [0.5,1): +-839 ulps per step (no RNE ties)
constexpr int STEP_ULPS = 839;
constexpr int TR = 12;                    // close_store rows/block; 3072/12 = 256 blocks

// ---------------- workspace layout (bytes) ----------------
constexpr size_t OFF_VB    = 0;                                    // 128 u32
constexpr size_t OFF_LCNT  = 512;                                  // 128 u32 (zeroed by k_seg_hist blk0)
constexpr size_t OFF_METAR = 1024;                                 // 128 u32
constexpr size_t OFF_METAB = 1536;                                 // 128 u32
constexpr size_t OFF_CNTS  = 2048;                                 // 512 u32
constexpr size_t OFF_PRIV  = 4096;                                 // 512*1025 u32
constexpr size_t OFF_SEG   = OFF_PRIV + (size_t)512 * (NBC + 1) * 4;
constexpr size_t OFF_LIST  = OFF_SEG + (size_t)512 * SEGCAP * 4;
constexpr size_t OFF_B     = OFF_LIST + (size_t)128 * CAP * 4;

__device__ __forceinline__ bool is_frame(int p) {
    int pr = p >> 3, pc = p & 7;
    return pr == 0 || pr == 7 || pc == 0 || pc == 7;
}

// Integer count boundaries reproducing fp32 mean/compare semantics (verified R1-R6)
__device__ void compute_ranks(bool frame, int& R1, int& R2) {
    float fb = frame ? 0.05f : 0.0f;
    float lo = 0.12f - fb;
    float hi = 0.08f - fb;
    int c = (int)((double)lo * 147456.0);
    while (c > 0 && (float)(c - 1) / 147456.0f >= lo) --c;
    while ((float)c / 147456.0f < lo) ++c;
    int d = (int)((double)hi * 147456.0);
    while ((float)(d + 1) / 147456.0f <= hi) ++d;
    while (d > 0 && (float)d / 147456.0f > hi) --d;
    R1 = c - 1;   // 0-indexed descending rank of v1 (K_lo-th largest)
    R2 = d;       // 0-indexed descending rank of v2 ((C_hi+1)-th largest)
}

// ---------------- K1: coarse hist + window compaction (single x read) ----------
// 512 blocks = 64 patches x 8 slices of 48 rows. Per-slice 1024-bin coarse hist
// (plain global stores) AND window keys (>= 0.75) appended to a private segment.
// Block 0 zeroes the list counters consumed two kernels later.
__global__ __launch_bounds__(256) void k_seg_hist(const float* __restrict__ x,
                                                  uint32_t* __restrict__ priv,
                                                  uint32_t* __restrict__ seg,
                                                  uint32_t* __restrict__ cnt_s,
                                                  uint32_t* __restrict__ listcnt) {
    __shared__ uint32_t hist[NBC + 1];
    __shared__ uint32_t lcnt;
    const int s = blockIdx.x & 7;
    const int p = blockIdx.x >> 3;
    const int t = threadIdx.x;
    const int pr = p >> 3, pc = p & 7;
    const float* base = x + (size_t)(pr * PH + s * SROWS) * IMG + pc * PH;
    uint32_t* myseg = seg + (size_t)blockIdx.x * SEGCAP;

    if (blockIdx.x == 0 && t < 128) listcnt[t] = 0;
    for (int i = t; i < NBC + 1; i += 256) hist[i] = 0;
    if (t == 0) lcnt = 0;
    __syncthreads();

    constexpr int NF4 = SROWS * (PH / 4);  // 4608
    for (int i = t; i < NF4; i += 256) {
        int r = i / 96, c = i - r * 96;
        float4 v = *reinterpret_cast<const float4*>(base + (size_t)r * IMG + c * 4);
        float vals[4] = {v.x, v.y, v.z, v.w};
#pragma unroll
        for (int k = 0; k < 4; ++k) {
            uint32_t key = __float_as_uint(vals[k]);
            if (key >= KEY_LO) {
                if (key < KEY_HI) atomicAdd(&hist[(key - KEY_LO) >> 13], 1u);
                else              atomicAdd(&hist[NBC], 1u);
            }
            if (key >= WLO) {
                uint32_t idx = atomicAdd(&lcnt, 1u);
                if (idx < SEGCAP) myseg[idx] = key;
            }
        }
    }
    __syncthreads();
    uint32_t* out = priv + (size_t)blockIdx.x * (NBC + 1);
    for (int i = t; i < NBC + 1; i += 256) out[i] = hist[i];
    if (t == 0) cnt_s[blockIdx.x] = (lcnt < SEGCAP) ? lcnt : SEGCAP;
}

// ---------------- K2: combine + bin-locate (replicated) + candidate append ----
// 512 blocks (8 replicas/patch). Replica s scans its OWN segment (not x) for
// keys in the two selected coarse bins -> per-(patch,j) global lists.
__global__ __launch_bounds__(256) void k_refine(const uint32_t* __restrict__ priv,
                                                const uint32_t* __restrict__ seg,
                                                const uint32_t* __restrict__ cnt_s,
                                                uint32_t* __restrict__ list,
                                                uint32_t* __restrict__ count,
                                                uint32_t* __restrict__ meta_r,
                                                uint32_t* __restrict__ meta_b) {
    __shared__ uint32_t comb[NBC + 1];
    __shared__ uint32_t partials[256];   // 4 desc bins each
    __shared__ uint32_t partial2[16];    // 16 partials each
    __shared__ uint32_t sel_bin_s[2];
    const int p = blockIdx.x >> 3, s = blockIdx.x & 7;
    const int t = threadIdx.x;

    for (int i = t; i < NBC + 1; i += 256) {
        uint32_t sum = 0;
#pragma unroll
        for (int b = 0; b < NSLICE; ++b)
            sum += priv[(size_t)(p * NSLICE + b) * (NBC + 1) + i];
        comb[i] = sum;
    }
    __syncthreads();
    {
        uint32_t sum = 0;
#pragma unroll
        for (int k = 0; k < 4; ++k) sum += comb[NBC - 1 - (4 * t + k)];
        partials[t] = sum;
    }
    __syncthreads();
    if (t < 16) {
        uint32_t sum = 0;
#pragma unroll
        for (int k = 0; k < 16; ++k) sum += partials[16 * t + k];
        partial2[t] = sum;
    }
    __syncthreads();
    if (t == 0) {
        uint32_t above = comb[NBC];
        uint32_t total = above;
        for (int u = 0; u < 16; ++u) total += partial2[u];
        int R[2];
        compute_ranks(is_frame(p), R[0], R[1]);
        for (int j = 0; j < 2; ++j) {
            int rank = R[j];
            if (rank < (int)above)  rank = (int)above;       // safety: v >= 1.0
            if (rank >= (int)total) rank = (int)total - 1;   // safety: v < 0.5
            uint32_t cum = above;
            int u = 15;
            for (int i = 0; i < 16; ++i) {
                if ((uint32_t)rank < cum + partial2[i]) { u = i; break; }
                cum += partial2[i];
            }
            int kk = 15;
            for (int i = 0; i < 16; ++i) {
                if ((uint32_t)rank < cum + partials[16 * u + i]) { kk = i; break; }
                cum += partials[16 * u + i];
            }
            int base_d = 4 * (16 * u + kk);
            uint32_t bin = NBC - 1 - base_d, r = 0;
            for (int b = 0; b < 4; ++b) {
                uint32_t h = comb[NBC - 1 - (base_d + b)];
                if ((uint32_t)rank < cum + h) { bin = NBC - 1 - (base_d + b); r = (uint32_t)rank - cum; break; }
                cum += h;
            }
            sel_bin_s[j] = bin;
            if (s == 0) { meta_b[p * 2 + j] = bin; meta_r[p * 2 + j] = r; }
        }
    }
    __syncthreads();
    const uint32_t b0 = sel_bin_s[0], b1 = sel_bin_s[1];
    const uint32_t* sg = seg + (size_t)blockIdx.x * SEGCAP;
    const uint32_t n = cnt_s[blockIdx.x];
    for (uint32_t i = t; i < n; i += 256) {
        uint32_t key = sg[i];
        if (key < KEY_HI) {
            uint32_t bin = (key - KEY_LO) >> 13;
            if (bin == b0) {
                uint32_t idx = atomicAdd(&count[p * 2 + 0], 1u);
                if (idx < CAP) list[(size_t)(p * 2 + 0) * CAP + idx] = key;
            }
            if (bin == b1) {
                uint32_t idx = atomicAdd(&count[p * 2 + 1], 1u);
                if (idx < CAP) list[(size_t)(p * 2 + 1) * CAP + idx] = key;
            }
        }
    }
}

// ---------------- K3: exact r-th largest from candidate list (one wave/slot) ---
__global__ __launch_bounds__(64) void k_select(const uint32_t* __restrict__ list,
                                               const uint32_t* __restrict__ count,
                                               const uint32_t* __restrict__ meta_r,
                                               const uint32_t* __restrict__ meta_b,
                                               uint32_t* __restrict__ vbits) {
    __shared__ uint32_t keys[CAP];
    __shared__ uint32_t res;
    const int slot = blockIdx.x;
    const int t = threadIdx.x;
    uint32_t n = count[slot]; if (n > CAP) n = CAP;
    uint32_t r = meta_r[slot];
    if (t == 0) res = KEY_LO + (meta_b[slot] << 13);  // fallback (unreachable)
    for (uint32_t i = t; i < n; i += 64) keys[i] = list[(size_t)slot * CAP + i];
    __syncthreads();
    for (uint32_t ci = t; ci < n; ci += 64) {
        uint32_t c = keys[ci], gt = 0, ge = 0;
        for (uint32_t i = 0; i < n; ++i) {
            uint32_t k = keys[i];
            gt += (k > c);
            ge += (k >= c);
        }
        if (gt <= r && r < ge) res = c;  // duplicates write the same value
    }
    __syncthreads();
    if (t == 0) vbits[slot] = res;
}

// ---------------- pack: th chain (in-block) + binarize + bit-pack (verified) ---
__global__ __launch_bounds__(256) void k_pack(const float* __restrict__ x,
                                              const uint32_t* __restrict__ vbits,
                                              uint32_t* __restrict__ B) {
    __shared__ uint32_t vb[128];
    __shared__ float ths_s[NPATCH];
    int t = threadIdx.x;
    if (t < 128) vb[t] = vbits[t];
    __syncthreads();
    if (t == 0) {
        uint32_t b = 0x3F59999Au;  // bits(0.85f)
        for (int p = 0; p < NPATCH; ++p) {
            uint32_t bv1 = vb[2 * p], bv2 = vb[2 * p + 1];
            int d1 = (int)b - (int)bv1;
            if (d1 >= 0) b -= (uint32_t)(STEP_ULPS * (d1 / STEP_ULPS + 1));
            int d2 = (int)bv2 - (int)b;
            if (d2 > 0) b += (uint32_t)(STEP_ULPS * ((d2 + STEP_ULPS - 1) / STEP_ULPS));
            ths_s[p] = __uint_as_float(b);
        }
    }
    __syncthreads();
    int wi = blockIdx.x * 256 + t;
    if (wi >= NWORDS) return;
    int y  = wi / WPR;
    int wx = wi - y * WPR;
    float th = ths_s[(y / PH) * 8 + (wx * 32) / PH];
    const float* row = x + (size_t)y * IMG + wx * 32;
    uint32_t m = 0;
#pragma unroll
    for (int k = 0; k < 8; ++k) {
        float4 v = *reinterpret_cast<const float4*>(row + 4 * k);
        m |= (uint32_t)(v.x > th) << (4 * k + 0);
        m |= (uint32_t)(v.y > th) << (4 * k + 1);
        m |= (uint32_t)(v.z > th) << (4 * k + 2);
        m |= (uint32_t)(v.w > th) << (4 * k + 3);
    }
    B[wi] = m;
}

// ---------------- fused 5x5 close + f32 store, row-tile + halo in LDS ----------
__device__ __forceinline__ uint32_t hshift5_or(uint32_t c, uint32_t l, uint32_t r) {
    uint64_t xr = ((uint64_t)r << 32) | c;
    uint64_t xl = ((uint64_t)c << 32) | l;
    return c | (uint32_t)(xr >> 1) | (uint32_t)(xr >> 2)
             | (uint32_t)(xl >> 31) | (uint32_t)(xl >> 30);
}
__device__ __forceinline__ uint32_t hshift5_and(uint32_t c, uint32_t l, uint32_t r) {
    uint64_t xr = ((uint64_t)r << 32) | c;
    uint64_t xl = ((uint64_t)c << 32) | l;
    return c & (uint32_t)(xr >> 1) & (uint32_t)(xr >> 2)
             & (uint32_t)(xl >> 31) & (uint32_t)(xl >> 30);
}

__global__ __launch_bounds__(256) void k_close_store(const uint32_t* __restrict__ B,
                                                     float* __restrict__ out) {
    __shared__ uint32_t Bs[TR + 8][WPR];   // binary rows [y0-4, y0+TR+4)
    __shared__ uint32_t Ds[TR + 4][WPR];   // dilated rows [y0-2, y0+TR+2)
    const int y0 = blockIdx.x * TR;
    const int t = threadIdx.x;

    for (int i = t; i < (TR + 8) * WPR; i += 256) {
        int r = i / WPR, c = i - r * WPR;
        int gy = y0 - 4 + r;
        Bs[r][c] = (gy >= 0 && gy < IMG) ? B[gy * WPR + c] : 0u;
    }
    __syncthreads();

    for (int i = t; i < (TR + 4) * WPR; i += 256) {
        int r = i / WPR, c = i - r * WPR;
        uint32_t acc = 0;
#pragma unroll
        for (int dy = -2; dy <= 2; ++dy) {
            int br = r + 2 + dy;
            uint32_t cc = Bs[br][c];
            uint32_t ll = (c > 0)       ? Bs[br][c - 1] : 0u;
            uint32_t rr = (c < WPR - 1) ? Bs[br][c + 1] : 0u;
            acc |= hshift5_or(cc, ll, rr);
        }
        Ds[r][c] = acc;
    }
    __syncthreads();

    for (int i = t; i < TR * WPR; i += 256) {
        int r = i / WPR, c = i - r * WPR;
        int gy = y0 + r;
        uint32_t acc = 0xFFFFFFFFu;
#pragma unroll
        for (int dy = -2; dy <= 2; ++dy) {
            int yy = gy + dy;
            if (yy < 0 || yy >= IMG) continue;
            int dr = r + 2 + dy;
            uint32_t cc = Ds[dr][c];
            uint32_t ll = (c > 0)       ? Ds[dr][c - 1] : 0xFFFFFFFFu;
            uint32_t rr = (c < WPR - 1) ? Ds[dr][c + 1] : 0xFFFFFFFFu;
            acc &= hshift5_and(cc, ll, rr);
        }
        float* o = out + (size_t)gy * IMG + c * 32;
#pragma unroll
        for (int k = 0; k < 8; ++k) {
            float4 v;
            v.x = (acc & (1u << (4 * k + 0))) ? 1.0f : 0.0f;
            v.y = (acc & (1u << (4 * k + 1))) ? 1.0f : 0.0f;
            v.z = (acc & (1u << (4 * k + 2))) ? 1.0f : 0.0f;
            v.w = (acc & (1u << (4 * k + 3))) ? 1.0f : 0.0f;
            *reinterpret_cast<float4*>(o + 4 * k) = v;
        }
    }
}

extern "C" void kernel_launch(void* const* d_in, const int* in_sizes, int n_in,
                              void* d_out, int out_size, void* d_ws, size_t ws_size,
                              hipStream_t stream) {
    const float* x = (const float*)d_in[0];
    float* out = (float*)d_out;
    uint8_t* ws = (uint8_t*)d_ws;

    uint32_t* vbits   = (uint32_t*)(ws + OFF_VB);
    uint32_t* listcnt = (uint32_t*)(ws + OFF_LCNT);
    uint32_t* meta_r  = (uint32_t*)(ws + OFF_METAR);
    uint32_t* meta_b  = (uint32_t*)(ws + OFF_METAB);
    uint32_t* cnt_s   = (uint32_t*)(ws + OFF_CNTS);
    uint32_t* priv    = (uint32_t*)(ws + OFF_PRIV);
    uint32_t* seg     = (uint32_t*)(ws + OFF_SEG);
    uint32_t* list    = (uint32_t*)(ws + OFF_LIST);
    uint32_t* Bb      = (uint32_t*)(ws + OFF_B);

    int gw = NWORDS / 256;  // 1152, exact

    k_seg_hist<<<NPATCH * NSLICE, 256, 0, stream>>>(x, priv, seg, cnt_s, listcnt);
    k_refine<<<NPATCH * NSLICE, 256, 0, stream>>>(priv, seg, cnt_s, list, listcnt, meta_r, meta_b);
    k_select<<<128, 64, 0, stream>>>(list, listcnt, meta_r, meta_b, vbits);
    k_pack<<<gw, 256, 0, stream>>>(x, vbits, Bb);
    k_close_store<<<IMG / TR, 256, 0, stream>>>(Bb, out);
}